// Round 4
// baseline (208.567 us; speedup 1.0000x reference)
//
#include <hip/hip_runtime.h>
#include <hip/hip_cooperative_groups.h>

namespace cg = cooperative_groups;

// LabPool: out[d,l] = max_n( labmap[l,n] * X[d,n] ), labmap one-hot over l.
// Zeros always participate -> out[d,l] = max(0, max_{label(n)=l} X[d,n]).
// Non-negative results -> uint bit ordering == float ordering.
//
// Single cooperative dispatch:
//   phase 1: lane = feature d, item wave-uniform -> LDS max table per block
//            (table stride 33, X-tile stride 65: all LDS ops 2-way banked = free,
//             label wave-uniform -> 64 distinct ds_max addresses, no serialization)
//   grid.sync()
//   phase 2: blocks 0..63 reduce the 768 tables (L2/L3-hot) -> d_out.

constexpr int L = 32;
constexpr int D = 64;            // == wave size
constexpr int TI = 64;           // items/tile; 200000/64 = 3125 tiles
constexpr int NB = 768;          // 3 blocks/CU * 256 CU (co-resident)
constexpr int XS_STRIDE = 65;
constexpr int SM_STRIDE = 33;
constexpr int SM_SIZE = D * SM_STRIDE;  // 2112

__device__ __forceinline__ void labpool_phase1(const float* __restrict__ labmap,
                                               const float* __restrict__ X,
                                               unsigned* __restrict__ tables,
                                               int N, int ntiles)
{
    __shared__ float    Xs[2][D * XS_STRIDE];
    __shared__ unsigned Ls[2][TI];
    __shared__ unsigned sm[SM_SIZE];

    const int tid  = threadIdx.x;
    const int wave = tid >> 6;
    const int lane = tid & 63;

    for (int i = tid; i < SM_SIZE; i += 256) sm[i] = 0u;

    int t = blockIdx.x;

    if (t < ntiles) {
        const int n0 = t * TI;
#pragma unroll
        for (int k = 0; k < 4; ++k) {
            const int q = tid + 256 * k;
            const int d = q >> 4, c = q & 15;
            const float4 x = *reinterpret_cast<const float4*>(X + (size_t)d * N + n0 + 4 * c);
            *reinterpret_cast<float4*>(&Xs[0][d * XS_STRIDE + 4 * c]) = x;
        }
        if (wave == 0) {
            float acc = 0.f;
#pragma unroll
            for (int l = 0; l < L; ++l)
                acc = fmaf((float)l, labmap[(size_t)l * N + n0 + lane], acc);
            Ls[0][lane] = (unsigned)acc;
        }
    }
    __syncthreads();

    int cur = 0;
    for (; t < ntiles; t += NB) {
        const int tn = t + NB;
        const bool have_next = (tn < ntiles);

        float4 xst[4];
        float acc = 0.f;
        if (have_next) {
            const int n0 = tn * TI;
#pragma unroll
            for (int k = 0; k < 4; ++k) {
                const int q = tid + 256 * k;
                const int d = q >> 4, c = q & 15;
                xst[k] = *reinterpret_cast<const float4*>(X + (size_t)d * N + n0 + 4 * c);
            }
            if (wave == (t & 3)) {
#pragma unroll
                for (int l = 0; l < L; ++l)
                    acc = fmaf((float)l, labmap[(size_t)l * N + tn * TI - tn * TI + n0 + lane], acc);
            }
        }

        {
            const int laneX = lane * XS_STRIDE;
            const int laneS = lane * SM_STRIDE;
#pragma unroll
            for (int j = 0; j < TI / 4; ++j) {
                const int i = wave * (TI / 4) + j;
                const unsigned lab = Ls[cur][i];
                const float x = Xs[cur][laneX + i];
                atomicMax(&sm[laneS + lab], __float_as_uint(fmaxf(x, 0.f)));
            }
        }

        if (have_next) {
            const int nxt = cur ^ 1;
#pragma unroll
            for (int k = 0; k < 4; ++k) {
                const int q = tid + 256 * k;
                const int d = q >> 4, c = q & 15;
                *reinterpret_cast<float4*>(&Xs[nxt][d * XS_STRIDE + 4 * c]) = xst[k];
            }
            if (wave == (t & 3)) Ls[nxt][lane] = (unsigned)acc;
        }
        __syncthreads();
        cur ^= 1;
    }

    unsigned* dst = tables + (size_t)blockIdx.x * SM_SIZE;
    for (int i = tid; i < SM_SIZE; i += 256) dst[i] = sm[i];
}

__global__ __launch_bounds__(256, 3)
void labpool_coop(const float* __restrict__ labmap,
                  const float* __restrict__ X,
                  unsigned* __restrict__ tables,
                  float* __restrict__ out,
                  int N, int ntiles)
{
    labpool_phase1(labmap, X, tables, N, ntiles);

    __threadfence();
    cg::this_grid().sync();

    if (blockIdx.x < (unsigned)D) {
        __shared__ unsigned red[8][32];
        const int tid = threadIdx.x;
        const int bq = tid >> 5, sl = tid & 31;
        const int d = blockIdx.x;
        unsigned m = 0u;
#pragma unroll 8
        for (int b = bq; b < NB; b += 8) {
            const unsigned v = tables[(size_t)b * SM_SIZE + d * SM_STRIDE + sl];
            m = (v > m) ? v : m;
        }
        red[bq][sl] = m;
        __syncthreads();
        if (bq == 0) {
            unsigned r = red[0][sl];
#pragma unroll
            for (int q = 1; q < 8; ++q) {
                const unsigned v = red[q][sl];
                r = (v > r) ? v : r;
            }
            out[d * L + sl] = __uint_as_float(r);
        }
    }
}

// ---- fallback path: proven 2-kernel version (round 3) ----
__global__ __launch_bounds__(256, 3)
void labpool_main(const float* __restrict__ labmap,
                  const float* __restrict__ X,
                  unsigned* __restrict__ tables, int N, int ntiles)
{
    labpool_phase1(labmap, X, tables, N, ntiles);
}

__global__ __launch_bounds__(256)
void labpool_reduce(const unsigned* __restrict__ tables, float* __restrict__ out, int nb)
{
    __shared__ unsigned red[8][32];
    const int tid = threadIdx.x;
    const int bq = tid >> 5, sl = tid & 31;
    const int d = blockIdx.x;
    unsigned m = 0u;
#pragma unroll 8
    for (int b = bq; b < nb; b += 8) {
        const unsigned v = tables[(size_t)b * SM_SIZE + d * SM_STRIDE + sl];
        m = (v > m) ? v : m;
    }
    red[bq][sl] = m;
    __syncthreads();
    if (bq == 0) {
        unsigned r = red[0][sl];
#pragma unroll
        for (int q = 1; q < 8; ++q) {
            const unsigned v = red[q][sl];
            r = (v > r) ? v : r;
        }
        out[d * L + sl] = __uint_as_float(r);
    }
}

extern "C" void kernel_launch(void* const* d_in, const int* in_sizes, int n_in,
                              void* d_out, int out_size, void* d_ws, size_t ws_size,
                              hipStream_t stream)
{
    const float* labmap = (const float*)d_in[0];   // [L, N]
    const float* X      = (const float*)d_in[1];   // [D, N]
    int N = in_sizes[0] / L;                       // 200000
    int ntiles = N / TI;                           // 3125

    unsigned* tables = (unsigned*)d_ws;
    float* out = (float*)d_out;

    void* args[] = { (void*)&labmap, (void*)&X, (void*)&tables, (void*)&out,
                     (void*)&N, (void*)&ntiles };
    hipError_t e = hipLaunchCooperativeKernel((const void*)labpool_coop,
                                              dim3(NB), dim3(256), args, 0, stream);
    if (e != hipSuccess) {
        labpool_main<<<NB, 256, 0, stream>>>(labmap, X, tables, N, ntiles);
        labpool_reduce<<<D, 256, 0, stream>>>(tables, out, NB);
    }
}

// Round 5
// 24.256 us; speedup vs baseline: 8.5985x; 8.5985x over previous
//
#include <hip/hip_runtime.h>

// LabPool: out[d,l] = max_n( labmap[l,n] * X[d,n] ), labmap one-hot over l.
// Zeros always participate -> out[d,l] = max(0, max_{label(n)=l} X[d,n]).
// Non-negative results -> uint bit ordering == float ordering (ds_max_u32).
//
// NOTE (round-4 lesson): hipLaunchCooperativeKernel collapsed HBM BW to
// 240 GB/s (6x slowdown) for identical code — never use coop launch here.
//
// Phase-1 layout: lane = feature d (64 lanes = D), item wave-uniform.
//   - label per item is wave-uniform at use (v_readlane -> SGPR): the 64
//     ds_max lanes hit distinct addresses, banks (lane+lab)%32 = 2-way (free).
//   - X-tile LDS stride 65 -> column read banks (lane+i)%32 = 2-way (free).
//   - labels decoded per-wave with all 64 lanes: 8 coalesced labmap row loads,
//     fmaf(l, m) partials, 2x shfl_xor to sum the 4 lane-groups (exact: one-hot).
//   - single-buffered Xs (26 KB LDS) + issue-early register staging of tile
//     t+NB before consuming tile t; 4 blocks/CU for TLP.

constexpr int L = 32;
constexpr int D = 64;            // == wave size
constexpr int TI = 64;           // items/tile; 200000/64 = 3125 tiles
constexpr int NB = 1024;         // 4 blocks/CU * 256 CU
constexpr int XS_STRIDE = 65;
constexpr int SM_STRIDE = 33;
constexpr int SM_SIZE = D * SM_STRIDE;  // 2112

__global__ __launch_bounds__(256, 4)
void labpool_main(const float* __restrict__ labmap,
                  const float* __restrict__ X,
                  unsigned* __restrict__ tables, int N, int ntiles)
{
    __shared__ float    Xs[D * XS_STRIDE];   // 16.6 KB
    __shared__ unsigned sm[SM_SIZE];         // 8.4 KB

    const int tid  = threadIdx.x;
    const int wave = tid >> 6;
    const int lane = tid & 63;
    const int item  = lane & 15;             // decode: item within wave's 16
    const int lrow0 = (lane >> 4) * 8;       // decode: this lane's 8 labmap rows

    unsigned* dst = tables + (size_t)blockIdx.x * SM_SIZE;

    if (blockIdx.x >= ntiles) {              // no tiles: emit zero table
        for (int i = tid; i < SM_SIZE; i += 256) dst[i] = 0u;
        return;
    }

    for (int i = tid; i < SM_SIZE; i += 256) sm[i] = 0u;

    const int laneX = lane * XS_STRIDE + wave * 16;
    const int laneS = lane * SM_STRIDE;
    const int d0 = tid >> 4, c4 = 4 * (tid & 15);

    int t = blockIdx.x;

    // ---- prologue: stage tile t into registers ----
    float4 xr0, xr1, xr2, xr3;
    unsigned labv;
    {
        const float* Xp = X + t * TI;
        xr0 = *reinterpret_cast<const float4*>(Xp + (size_t)(d0)      * N + c4);
        xr1 = *reinterpret_cast<const float4*>(Xp + (size_t)(d0 + 16) * N + c4);
        xr2 = *reinterpret_cast<const float4*>(Xp + (size_t)(d0 + 32) * N + c4);
        xr3 = *reinterpret_cast<const float4*>(Xp + (size_t)(d0 + 48) * N + c4);
        const float* mp = labmap + (size_t)lrow0 * N + t * TI + wave * 16 + item;
        float acc = 0.f;
#pragma unroll
        for (int ll = 0; ll < 8; ++ll)
            acc = fmaf((float)(lrow0 + ll), mp[(size_t)ll * N], acc);
        acc += __shfl_xor(acc, 32);
        acc += __shfl_xor(acc, 16);
        labv = (unsigned)acc;
    }

    while (true) {
        // write current tile's registers to LDS
        *reinterpret_cast<float4*>(&Xs[(d0)      * XS_STRIDE + c4]) = xr0;
        *reinterpret_cast<float4*>(&Xs[(d0 + 16) * XS_STRIDE + c4]) = xr1;
        *reinterpret_cast<float4*>(&Xs[(d0 + 32) * XS_STRIDE + c4]) = xr2;
        *reinterpret_cast<float4*>(&Xs[(d0 + 48) * XS_STRIDE + c4]) = xr3;
        __syncthreads();                     // (b) Xs ready

        const int tn = t + NB;
        const bool have_next = (tn < ntiles);

        // issue next tile's global loads early (latency hides under consume)
        float acc2 = 0.f;
        if (have_next) {
            const float* Xp = X + tn * TI;
            xr0 = *reinterpret_cast<const float4*>(Xp + (size_t)(d0)      * N + c4);
            xr1 = *reinterpret_cast<const float4*>(Xp + (size_t)(d0 + 16) * N + c4);
            xr2 = *reinterpret_cast<const float4*>(Xp + (size_t)(d0 + 32) * N + c4);
            xr3 = *reinterpret_cast<const float4*>(Xp + (size_t)(d0 + 48) * N + c4);
            const float* mp = labmap + (size_t)lrow0 * N + tn * TI + wave * 16 + item;
#pragma unroll
            for (int ll = 0; ll < 8; ++ll)
                acc2 = fmaf((float)(lrow0 + ll), mp[(size_t)ll * N], acc2);
        }

        // consume tile t: 16 items per wave, lane = d, label via v_readlane
#pragma unroll
        for (int j = 0; j < 16; ++j) {
            const int labj = __builtin_amdgcn_readlane((int)labv, j);
            const float x = Xs[laneX + j];
            atomicMax(&sm[laneS + labj], __float_as_uint(fmaxf(x, 0.f)));
        }

        if (!have_next) break;

        acc2 += __shfl_xor(acc2, 32);
        acc2 += __shfl_xor(acc2, 16);
        labv = (unsigned)acc2;
        t = tn;
        __syncthreads();                     // (a) all waves done reading Xs
    }

    __syncthreads();                         // all waves' sm atomics done
    for (int i = tid; i < SM_SIZE; i += 256) dst[i] = sm[i];
}

__global__ __launch_bounds__(512)
void labpool_reduce(const unsigned* __restrict__ tables, float* __restrict__ out, int nb)
{
    __shared__ unsigned red[16][32];
    const int tid = threadIdx.x;
    const int bq = tid >> 5;      // 0..15
    const int sl = tid & 31;
    const int d  = blockIdx.x;    // 64 blocks
    unsigned m = 0u;
#pragma unroll 8
    for (int b = bq; b < nb; b += 16) {
        const unsigned v = tables[(size_t)b * SM_SIZE + d * SM_STRIDE + sl];
        m = (v > m) ? v : m;
    }
    red[bq][sl] = m;
    __syncthreads();
    if (bq == 0) {
        unsigned r = red[0][sl];
#pragma unroll
        for (int q = 1; q < 16; ++q) {
            const unsigned v = red[q][sl];
            r = (v > r) ? v : r;
        }
        out[d * L + sl] = __uint_as_float(r);
    }
}

// ---- fallback (tiny ws): fused kernel with global atomics ----
__global__ __launch_bounds__(256)
void labpool_fused_atomic(const float* __restrict__ labmap,
                          const float* __restrict__ X,
                          unsigned* __restrict__ gout, int N)
{
    __shared__ unsigned sm2[D * L];
    __shared__ unsigned char lab[400];
    const int tid = threadIdx.x;
    const int n0 = blockIdx.x * 400;
    for (int i = tid; i < D * L; i += 256) sm2[i] = 0u;
    constexpr int V = 100;
    for (int idx = tid; idx < L * V; idx += 256) {
        const int l = idx / V;
        const int v = idx - l * V;
        const float4 m = *reinterpret_cast<const float4*>(labmap + (size_t)l * N + n0 + 4 * v);
        if (m.x > 0.5f) lab[4 * v + 0] = (unsigned char)l;
        if (m.y > 0.5f) lab[4 * v + 1] = (unsigned char)l;
        if (m.z > 0.5f) lab[4 * v + 2] = (unsigned char)l;
        if (m.w > 0.5f) lab[4 * v + 3] = (unsigned char)l;
    }
    __syncthreads();
    for (int idx = tid; idx < D * V; idx += 256) {
        const int d = idx / V;
        const int v = idx - d * V;
        const float4 x = *reinterpret_cast<const float4*>(X + (size_t)d * N + n0 + 4 * v);
        const uchar4 lv = *reinterpret_cast<const uchar4*>(&lab[4 * v]);
        atomicMax(&sm2[d * L + lv.x], __float_as_uint(fmaxf(x.x, 0.f)));
        atomicMax(&sm2[d * L + lv.y], __float_as_uint(fmaxf(x.y, 0.f)));
        atomicMax(&sm2[d * L + lv.z], __float_as_uint(fmaxf(x.z, 0.f)));
        atomicMax(&sm2[d * L + lv.w], __float_as_uint(fmaxf(x.w, 0.f)));
    }
    __syncthreads();
    for (int i = tid; i < D * L; i += 256) atomicMax(&gout[i], sm2[i]);
}

__global__ void zero_out_k(unsigned* p, int n)
{
    const int i = blockIdx.x * 256 + threadIdx.x;
    if (i < n) p[i] = 0u;
}

extern "C" void kernel_launch(void* const* d_in, const int* in_sizes, int n_in,
                              void* d_out, int out_size, void* d_ws, size_t ws_size,
                              hipStream_t stream)
{
    const float* labmap = (const float*)d_in[0];   // [L, N]
    const float* X      = (const float*)d_in[1];   // [D, N]
    const int N = in_sizes[0] / L;                 // 200000
    const int ntiles = N / TI;                     // 3125

    const size_t need = (size_t)NB * SM_SIZE * sizeof(unsigned);  // ~8.7 MB
    if (d_ws && ws_size >= need && (N % TI) == 0) {
        unsigned* tables = (unsigned*)d_ws;
        labpool_main<<<NB, 256, 0, stream>>>(labmap, X, tables, N, ntiles);
        labpool_reduce<<<D, 512, 0, stream>>>(tables, (float*)d_out, NB);
    } else {
        unsigned* gout = (unsigned*)d_out;
        zero_out_k<<<(D * L + 255) / 256, 256, 0, stream>>>(gout, D * L);
        labpool_fused_atomic<<<N / 400, 256, 0, stream>>>(labmap, X, gout, N);
    }
}

// Round 6
// 22.347 us; speedup vs baseline: 9.3332x; 1.0854x over previous
//
#include <hip/hip_runtime.h>

// LabPool: out[d,l] = max_n( labmap[l,n] * X[d,n] ), labmap one-hot over l.
// Zeros always participate -> out[d,l] = max(0, max_{label(n)=l} X[d,n]).
// Non-negative results -> uint bit ordering == float ordering (ds_max_u32).
//
// Lessons locked in: no hipLaunchCooperativeKernel (round 4: 6x BW collapse);
// lane = feature d, label wave-uniform at use (readlane) -> conflict-free DS.
//
// Round-6 structure: 512 blocks x 512 threads (8 waves; 2 blocks/CU = 16
// waves/CU), ~6.1 tiles/block, depth-2 register pipeline (slots A/B, loads
// for t+2NB issued after staging t), packed 2048-u32 tables (4.2 MB total),
// uint4-vectorized 128-block reduce.

constexpr int L = 32;
constexpr int D = 64;            // == wave size
constexpr int TI = 64;           // items/tile; 200000/64 = 3125 tiles
constexpr int NB = 512;          // blocks
constexpr int NT = 512;          // threads/block (8 waves)
constexpr int XS_STRIDE = 65;    // LDS X-tile row stride (2-way banks = free)
constexpr int SM_STRIDE = 33;    // LDS table row stride (2-way banks = free)
constexpr int SM_SIZE = D * SM_STRIDE;  // 2112
constexpr int TBL = D * L;       // packed global table (2048 u32)

__global__ __launch_bounds__(NT, 4)
void labpool_main(const float* __restrict__ labmap,
                  const float* __restrict__ X,
                  unsigned* __restrict__ tables, int N, int ntiles)
{
    __shared__ float    Xs[D * XS_STRIDE];   // 16.6 KB
    __shared__ unsigned sm[SM_SIZE];         // 8.4 KB

    const int tid  = threadIdx.x;
    const int wave = tid >> 6;
    const int lane = tid & 63;
    const int item  = lane & 7;              // decode: wave covers items wave*8..+7
    const int lrow0 = (lane >> 3) << 2;      // decode: 4 labmap rows per 8-lane group

    unsigned* dst = tables + (size_t)blockIdx.x * TBL;
    if ((int)blockIdx.x >= ntiles) {         // no tiles: emit zero table
        for (int i = tid; i < TBL; i += NT) dst[i] = 0u;
        return;
    }

    for (int i = tid; i < SM_SIZE; i += NT) sm[i] = 0u;

    const int r0 = tid >> 4;                 // staging rows 0..31
    const int c0 = 4 * (tid & 15);
    const int r1 = r0 + 32;                  // staging rows 32..63
    const size_t rowOff0 = (size_t)r0 * N + c0;
    const size_t rowOff1 = (size_t)r1 * N + c0;
    const float* mbase = labmap + (size_t)lrow0 * N + wave * 8 + item;

    const int laneX = lane * XS_STRIDE + wave * 8;
    const int laneS = lane * SM_STRIDE;

    auto LOAD = [&](int t, float4& x0, float4& x1, float (&m)[4]) {
        const int n0 = t * TI;
        x0 = *reinterpret_cast<const float4*>(X + rowOff0 + n0);
        x1 = *reinterpret_cast<const float4*>(X + rowOff1 + n0);
        const float* mp = mbase + n0;
        m[0] = mp[0];
        m[1] = mp[(size_t)N];
        m[2] = mp[(size_t)2 * N];
        m[3] = mp[(size_t)3 * N];
    };
    auto STAGE = [&](const float4& x0, const float4& x1) {
        *reinterpret_cast<float4*>(&Xs[r0 * XS_STRIDE + c0]) = x0;
        *reinterpret_cast<float4*>(&Xs[r1 * XS_STRIDE + c0]) = x1;
    };
    auto LABV = [&](const float (&m)[4]) -> unsigned {
        float acc =            (float)(lrow0)     * m[0];
        acc = fmaf((float)(lrow0 + 1), m[1], acc);
        acc = fmaf((float)(lrow0 + 2), m[2], acc);
        acc = fmaf((float)(lrow0 + 3), m[3], acc);
        acc += __shfl_xor(acc, 8);               // sum the 8 row-groups
        acc += __shfl_xor(acc, 16);
        acc += __shfl_xor(acc, 32);
        return (unsigned)acc;                    // exact small int
    };
    auto CONSUME = [&](unsigned labv) {
#pragma unroll
        for (int j = 0; j < 8; ++j) {
            const int labj = __builtin_amdgcn_readlane((int)labv, j); // wave-uniform
            const float x = Xs[laneX + j];                            // 2-way banks
            atomicMax(&sm[laneS + labj], __float_as_uint(fmaxf(x, 0.f)));
        }
    };

    int t = blockIdx.x;
    float4 xA0, xA1, xB0, xB1;
    float mA[4], mB[4];
    LOAD(t, xA0, xA1, mA);
    if (t + NB < ntiles) LOAD(t + NB, xB0, xB1, mB);

    while (true) {
        // ---- slot A holds tile t ----
        STAGE(xA0, xA1);
        const unsigned lvA = LABV(mA);           // uses old mA, before reload
        __syncthreads();                         // Xs ready
        if (t + 2 * NB < ntiles) LOAD(t + 2 * NB, xA0, xA1, mA);  // issue early
        CONSUME(lvA);
        t += NB;
        if (t >= ntiles) break;
        __syncthreads();                         // Xs free to overwrite

        // ---- slot B holds tile t ----
        STAGE(xB0, xB1);
        const unsigned lvB = LABV(mB);
        __syncthreads();
        if (t + 2 * NB < ntiles) LOAD(t + 2 * NB, xB0, xB1, mB);
        CONSUME(lvB);
        t += NB;
        if (t >= ntiles) break;
        __syncthreads();
    }

    __syncthreads();                             // drain all waves' sm atomics
    for (int i = tid; i < TBL; i += NT)
        dst[i] = sm[(i >> 5) * SM_STRIDE + (i & 31)];   // unpad on the way out
}

__global__ __launch_bounds__(256)
void labpool_reduce(const unsigned* __restrict__ tables, float* __restrict__ out, int nb)
{
    // 128 blocks: block = (d, half). Each handles 16 labels = 4 uint4 parts.
    __shared__ uint4 red[256];
    const int tid  = threadIdx.x;
    const int d    = blockIdx.x >> 1;
    const int h    = blockIdx.x & 1;
    const int part = tid & 3;
    const int g    = tid >> 2;                   // 64 table-groups
    const int base = d * L + h * 16 + part * 4;  // 16-B aligned

    uint4 m = make_uint4(0u, 0u, 0u, 0u);
    for (int b = g; b < nb; b += 64) {
        const uint4 v = *reinterpret_cast<const uint4*>(tables + (size_t)b * TBL + base);
        m.x = (v.x > m.x) ? v.x : m.x;
        m.y = (v.y > m.y) ? v.y : m.y;
        m.z = (v.z > m.z) ? v.z : m.z;
        m.w = (v.w > m.w) ? v.w : m.w;
    }
    red[tid] = m;
    __syncthreads();
#pragma unroll
    for (int s = 128; s >= 4; s >>= 1) {
        if (tid < s) {
            const uint4 v = red[tid + s];
            uint4 r = red[tid];
            r.x = (v.x > r.x) ? v.x : r.x;
            r.y = (v.y > r.y) ? v.y : r.y;
            r.z = (v.z > r.z) ? v.z : r.z;
            r.w = (v.w > r.w) ? v.w : r.w;
            red[tid] = r;
        }
        __syncthreads();
    }
    if (tid < 4) {
        const uint4 r = red[tid];
        float4 f;
        f.x = __uint_as_float(r.x);
        f.y = __uint_as_float(r.y);
        f.z = __uint_as_float(r.z);
        f.w = __uint_as_float(r.w);
        *reinterpret_cast<float4*>(out + d * L + h * 16 + tid * 4) = f;
    }
}

// ---- fallback (tiny ws): fused kernel with global atomics ----
__global__ __launch_bounds__(256)
void labpool_fused_atomic(const float* __restrict__ labmap,
                          const float* __restrict__ X,
                          unsigned* __restrict__ gout, int N)
{
    __shared__ unsigned sm2[D * L];
    __shared__ unsigned char lab[400];
    const int tid = threadIdx.x;
    const int n0 = blockIdx.x * 400;
    for (int i = tid; i < D * L; i += 256) sm2[i] = 0u;
    constexpr int V = 100;
    for (int idx = tid; idx < L * V; idx += 256) {
        const int l = idx / V;
        const int v = idx - l * V;
        const float4 m = *reinterpret_cast<const float4*>(labmap + (size_t)l * N + n0 + 4 * v);
        if (m.x > 0.5f) lab[4 * v + 0] = (unsigned char)l;
        if (m.y > 0.5f) lab[4 * v + 1] = (unsigned char)l;
        if (m.z > 0.5f) lab[4 * v + 2] = (unsigned char)l;
        if (m.w > 0.5f) lab[4 * v + 3] = (unsigned char)l;
    }
    __syncthreads();
    for (int idx = tid; idx < D * V; idx += 256) {
        const int d = idx / V;
        const int v = idx - d * V;
        const float4 x = *reinterpret_cast<const float4*>(X + (size_t)d * N + n0 + 4 * v);
        const uchar4 lv = *reinterpret_cast<const uchar4*>(&lab[4 * v]);
        atomicMax(&sm2[d * L + lv.x], __float_as_uint(fmaxf(x.x, 0.f)));
        atomicMax(&sm2[d * L + lv.y], __float_as_uint(fmaxf(x.y, 0.f)));
        atomicMax(&sm2[d * L + lv.z], __float_as_uint(fmaxf(x.z, 0.f)));
        atomicMax(&sm2[d * L + lv.w], __float_as_uint(fmaxf(x.w, 0.f)));
    }
    __syncthreads();
    for (int i = tid; i < D * L; i += 256) atomicMax(&gout[i], sm2[i]);
}

__global__ void zero_out_k(unsigned* p, int n)
{
    const int i = blockIdx.x * 256 + threadIdx.x;
    if (i < n) p[i] = 0u;
}

extern "C" void kernel_launch(void* const* d_in, const int* in_sizes, int n_in,
                              void* d_out, int out_size, void* d_ws, size_t ws_size,
                              hipStream_t stream)
{
    const float* labmap = (const float*)d_in[0];   // [L, N]
    const float* X      = (const float*)d_in[1];   // [D, N]
    const int N = in_sizes[0] / L;                 // 200000
    const int ntiles = N / TI;                     // 3125

    const size_t need = (size_t)NB * TBL * sizeof(unsigned);  // 4.2 MB
    if (d_ws && ws_size >= need && (N % TI) == 0) {
        unsigned* tables = (unsigned*)d_ws;
        labpool_main<<<NB, NT, 0, stream>>>(labmap, X, tables, N, ntiles);
        labpool_reduce<<<2 * D, 256, 0, stream>>>(tables, (float*)d_out, NB);
    } else {
        unsigned* gout = (unsigned*)d_out;
        zero_out_k<<<(D * L + 255) / 256, 256, 0, stream>>>(gout, D * L);
        labpool_fused_atomic<<<N / 400, 256, 0, stream>>>(labmap, X, gout, N);
    }
}

// Round 7
// 22.167 us; speedup vs baseline: 9.4087x; 1.0081x over previous
//
#include <hip/hip_runtime.h>

// LabPool: out[d,l] = max_n( labmap[l,n] * X[d,n] ), labmap one-hot over l.
// Zeros always participate -> out[d,l] = max(0, max_{label(n)=l} X[d,n]).
// Non-negative results -> uint bit ordering == float ordering (ds_max_u32).
//
// Locked-in lessons: no hipLaunchCooperativeKernel (R4: 6x BW collapse);
// lane = feature d with wave-uniform label at use (readlane) -> conflict-free
// DS; depth-2 register prefetch; packed 2048-u32 tables; no global atomics
// onto the tiny output (per-address L2 serialization).
//
// Round-7: double-buffered Xs -> ONE __syncthreads per tile (was 2).
// Per iteration: STAGE tile t+1 -> buf^1, compute its labels, issue LOAD of
// tile t+2, CONSUME tile t from buf, barrier. 41.7 KB LDS, 2 blocks/CU,
// 16 waves/CU.

constexpr int L = 32;
constexpr int D = 64;            // == wave size
constexpr int TI = 64;           // items/tile; 200000/64 = 3125 tiles
constexpr int NB = 512;          // blocks (2/CU)
constexpr int NT = 512;          // threads/block (8 waves)
constexpr int XS_STRIDE = 65;    // LDS X-tile row stride (2-way banks = free)
constexpr int SM_STRIDE = 33;    // LDS table row stride (2-way banks = free)
constexpr int SM_SIZE = D * SM_STRIDE;  // 2112
constexpr int TBL = D * L;       // packed global table (2048 u32)

__global__ __launch_bounds__(NT, 4)
void labpool_main(const float* __restrict__ labmap,
                  const float* __restrict__ X,
                  unsigned* __restrict__ tables, int N, int ntiles)
{
    __shared__ float    Xs[2][D * XS_STRIDE];  // 2 x 16.6 KB
    __shared__ unsigned sm[SM_SIZE];           // 8.4 KB

    const int tid  = threadIdx.x;
    const int wave = tid >> 6;
    const int lane = tid & 63;
    const int item  = lane & 7;              // decode: wave covers items wave*8..+7
    const int lrow0 = (lane >> 3) << 2;      // decode: 4 labmap rows per 8-lane group

    unsigned* dst = tables + (size_t)blockIdx.x * TBL;
    if ((int)blockIdx.x >= ntiles) {         // no tiles: emit zero table
        for (int i = tid; i < TBL; i += NT) dst[i] = 0u;
        return;
    }

    for (int i = tid; i < SM_SIZE; i += NT) sm[i] = 0u;

    const int r0 = tid >> 4;                 // staging rows 0..31
    const int c0 = 4 * (tid & 15);
    const int r1 = r0 + 32;                  // staging rows 32..63
    const size_t rowOff0 = (size_t)r0 * N + c0;
    const size_t rowOff1 = (size_t)r1 * N + c0;
    const float* mbase = labmap + (size_t)lrow0 * N + wave * 8 + item;

    const int laneX = lane * XS_STRIDE + wave * 8;
    const int laneS = lane * SM_STRIDE;

    float4 xr0, xr1;                         // single X register slot
    auto LOAD = [&](int t, float (&m)[4]) {
        const int n0 = t * TI;
        xr0 = *reinterpret_cast<const float4*>(X + rowOff0 + n0);
        xr1 = *reinterpret_cast<const float4*>(X + rowOff1 + n0);
        const float* mp = mbase + n0;
        m[0] = mp[0];
        m[1] = mp[(size_t)N];
        m[2] = mp[(size_t)2 * N];
        m[3] = mp[(size_t)3 * N];
    };
    auto STAGE = [&](int b) {
        *reinterpret_cast<float4*>(&Xs[b][r0 * XS_STRIDE + c0]) = xr0;
        *reinterpret_cast<float4*>(&Xs[b][r1 * XS_STRIDE + c0]) = xr1;
    };
    auto LABV = [&](const float (&m)[4]) -> unsigned {
        float acc =            (float)(lrow0)     * m[0];
        acc = fmaf((float)(lrow0 + 1), m[1], acc);
        acc = fmaf((float)(lrow0 + 2), m[2], acc);
        acc = fmaf((float)(lrow0 + 3), m[3], acc);
        acc += __shfl_xor(acc, 8);               // sum the 8 row-groups
        acc += __shfl_xor(acc, 16);
        acc += __shfl_xor(acc, 32);
        return (unsigned)acc;                    // exact small int
    };
    auto CONSUME = [&](int b, unsigned labv) {
#pragma unroll
        for (int j = 0; j < 8; ++j) {
            const int labj = __builtin_amdgcn_readlane((int)labv, j); // wave-uniform
            const float x = Xs[b][laneX + j];                          // 2-way banks
            atomicMax(&sm[laneS + labj], __float_as_uint(fmaxf(x, 0.f)));
        }
    };

    // ---- prologue: stage tile t into buf0, prefetch tile t+NB ----
    int t = blockIdx.x;
    float mA[4], mB[4];
    LOAD(t, mA);
    STAGE(0);
    unsigned lvA = LABV(mA);
    bool h1 = (t + NB < ntiles);
    if (h1) LOAD(t + NB, mB);
    __syncthreads();                             // buf0 ready

    while (true) {
        // ---- consume buf0 (tile t); stage tile t+NB -> buf1 ----
        if (h1) STAGE(1);                        // X regs hold tile t+NB
        const unsigned lvB = h1 ? LABV(mB) : 0u;
        if (t + 2 * NB < ntiles) LOAD(t + 2 * NB, mA);   // issue early
        CONSUME(0, lvA);
        __syncthreads();                         // stage(t+NB) done + consume(t) done
        if (!h1) break;
        t += NB;
        h1 = (t + NB < ntiles);

        // ---- consume buf1 (tile t); stage tile t+NB -> buf0 ----
        if (h1) STAGE(0);                        // X regs hold tile t+NB
        lvA = h1 ? LABV(mA) : 0u;
        if (t + 2 * NB < ntiles) LOAD(t + 2 * NB, mB);
        CONSUME(1, lvB);
        __syncthreads();
        if (!h1) break;
        t += NB;
        h1 = (t + NB < ntiles);
    }

    __syncthreads();                             // drain all waves' sm atomics
    for (int i = tid; i < TBL; i += NT)
        dst[i] = sm[(i >> 5) * SM_STRIDE + (i & 31)];   // unpad on the way out
}

__global__ __launch_bounds__(256)
void labpool_reduce(const unsigned* __restrict__ tables, float* __restrict__ out, int nb)
{
    // 128 blocks: block = (d, half). Each handles 16 labels = 4 uint4 parts.
    __shared__ uint4 red[256];
    const int tid  = threadIdx.x;
    const int d    = blockIdx.x >> 1;
    const int h    = blockIdx.x & 1;
    const int part = tid & 3;
    const int g    = tid >> 2;                   // 64 table-groups
    const int base = d * L + h * 16 + part * 4;  // 16-B aligned

    uint4 m = make_uint4(0u, 0u, 0u, 0u);
    for (int b = g; b < nb; b += 64) {
        const uint4 v = *reinterpret_cast<const uint4*>(tables + (size_t)b * TBL + base);
        m.x = (v.x > m.x) ? v.x : m.x;
        m.y = (v.y > m.y) ? v.y : m.y;
        m.z = (v.z > m.z) ? v.z : m.z;
        m.w = (v.w > m.w) ? v.w : m.w;
    }
    red[tid] = m;
    __syncthreads();
#pragma unroll
    for (int s = 128; s >= 4; s >>= 1) {
        if (tid < s) {
            const uint4 v = red[tid + s];
            uint4 r = red[tid];
            r.x = (v.x > r.x) ? v.x : r.x;
            r.y = (v.y > r.y) ? v.y : r.y;
            r.z = (v.z > r.z) ? v.z : r.z;
            r.w = (v.w > r.w) ? v.w : r.w;
            red[tid] = r;
        }
        __syncthreads();
    }
    if (tid < 4) {
        const uint4 r = red[tid];
        float4 f;
        f.x = __uint_as_float(r.x);
        f.y = __uint_as_float(r.y);
        f.z = __uint_as_float(r.z);
        f.w = __uint_as_float(r.w);
        *reinterpret_cast<float4*>(out + d * L + h * 16 + tid * 4) = f;
    }
}

// ---- fallback (tiny ws): fused kernel with global atomics ----
__global__ __launch_bounds__(256)
void labpool_fused_atomic(const float* __restrict__ labmap,
                          const float* __restrict__ X,
                          unsigned* __restrict__ gout, int N)
{
    __shared__ unsigned sm2[D * L];
    __shared__ unsigned char lab[400];
    const int tid = threadIdx.x;
    const int n0 = blockIdx.x * 400;
    for (int i = tid; i < D * L; i += 256) sm2[i] = 0u;
    constexpr int V = 100;
    for (int idx = tid; idx < L * V; idx += 256) {
        const int l = idx / V;
        const int v = idx - l * V;
        const float4 m = *reinterpret_cast<const float4*>(labmap + (size_t)l * N + n0 + 4 * v);
        if (m.x > 0.5f) lab[4 * v + 0] = (unsigned char)l;
        if (m.y > 0.5f) lab[4 * v + 1] = (unsigned char)l;
        if (m.z > 0.5f) lab[4 * v + 2] = (unsigned char)l;
        if (m.w > 0.5f) lab[4 * v + 3] = (unsigned char)l;
    }
    __syncthreads();
    for (int idx = tid; idx < D * V; idx += 256) {
        const int d = idx / V;
        const int v = idx - d * V;
        const float4 x = *reinterpret_cast<const float4*>(X + (size_t)d * N + n0 + 4 * v);
        const uchar4 lv = *reinterpret_cast<const uchar4*>(&lab[4 * v]);
        atomicMax(&sm2[d * L + lv.x], __float_as_uint(fmaxf(x.x, 0.f)));
        atomicMax(&sm2[d * L + lv.y], __float_as_uint(fmaxf(x.y, 0.f)));
        atomicMax(&sm2[d * L + lv.z], __float_as_uint(fmaxf(x.z, 0.f)));
        atomicMax(&sm2[d * L + lv.w], __float_as_uint(fmaxf(x.w, 0.f)));
    }
    __syncthreads();
    for (int i = tid; i < D * L; i += 256) atomicMax(&gout[i], sm2[i]);
}

__global__ void zero_out_k(unsigned* p, int n)
{
    const int i = blockIdx.x * 256 + threadIdx.x;
    if (i < n) p[i] = 0u;
}

extern "C" void kernel_launch(void* const* d_in, const int* in_sizes, int n_in,
                              void* d_out, int out_size, void* d_ws, size_t ws_size,
                              hipStream_t stream)
{
    const float* labmap = (const float*)d_in[0];   // [L, N]
    const float* X      = (const float*)d_in[1];   // [D, N]
    const int N = in_sizes[0] / L;                 // 200000
    const int ntiles = N / TI;                     // 3125

    const size_t need = (size_t)NB * TBL * sizeof(unsigned);  // 4.2 MB
    if (d_ws && ws_size >= need && (N % TI) == 0) {
        unsigned* tables = (unsigned*)d_ws;
        labpool_main<<<NB, NT, 0, stream>>>(labmap, X, tables, N, ntiles);
        labpool_reduce<<<2 * D, 256, 0, stream>>>(tables, (float*)d_out, NB);
    } else {
        unsigned* gout = (unsigned*)d_out;
        zero_out_k<<<(D * L + 255) / 256, 256, 0, stream>>>(gout, D * L);
        labpool_fused_atomic<<<N / 400, 256, 0, stream>>>(labmap, X, gout, N);
    }
}